// Round 1
// baseline (3825.544 us; speedup 1.0000x reference)
//
#include <hip/hip_runtime.h>

// NodeModel: agg = segment_sum(x[row], col); h = concat(x, agg);
// out = MLP(h) with Lin(6,16)-ReLU-Lin(16,16)-ReLU-Lin(16,3).
// d_out [N,3] fp32 doubles as the agg accumulator (zeroed, scattered into,
// then overwritten in-place by the per-node MLP).

__global__ __launch_bounds__(256) void edge_scatter_kernel(
    const int* __restrict__ rows, const int* __restrict__ cols,
    const float* __restrict__ x, float* __restrict__ agg, int n_edges)
{
    const long long tid = (long long)blockIdx.x * blockDim.x + threadIdx.x;
    const long long stride = (long long)gridDim.x * blockDim.x;
    const int n4 = n_edges >> 2;
    const int4* __restrict__ r4p = reinterpret_cast<const int4*>(rows);
    const int4* __restrict__ c4p = reinterpret_cast<const int4*>(cols);
    for (long long i = tid; i < n4; i += stride) {
        int4 r = r4p[i];
        int4 c = c4p[i];
        {
            const float* xs = x + 3ll * r.x; float* a = agg + 3ll * c.x;
            atomicAdd(a + 0, xs[0]); atomicAdd(a + 1, xs[1]); atomicAdd(a + 2, xs[2]);
        }
        {
            const float* xs = x + 3ll * r.y; float* a = agg + 3ll * c.y;
            atomicAdd(a + 0, xs[0]); atomicAdd(a + 1, xs[1]); atomicAdd(a + 2, xs[2]);
        }
        {
            const float* xs = x + 3ll * r.z; float* a = agg + 3ll * c.z;
            atomicAdd(a + 0, xs[0]); atomicAdd(a + 1, xs[1]); atomicAdd(a + 2, xs[2]);
        }
        {
            const float* xs = x + 3ll * r.w; float* a = agg + 3ll * c.w;
            atomicAdd(a + 0, xs[0]); atomicAdd(a + 1, xs[1]); atomicAdd(a + 2, xs[2]);
        }
    }
    // tail (n_edges not divisible by 4)
    for (long long i = (long long)(n4 << 2) + tid; i < n_edges; i += stride) {
        int r = rows[i], c = cols[i];
        const float* xs = x + 3ll * r; float* a = agg + 3ll * c;
        atomicAdd(a + 0, xs[0]); atomicAdd(a + 1, xs[1]); atomicAdd(a + 2, xs[2]);
    }
}

__global__ __launch_bounds__(256) void node_mlp_kernel(
    const float* __restrict__ x,
    const float* __restrict__ W1, const float* __restrict__ b1,
    const float* __restrict__ W2, const float* __restrict__ b2,
    const float* __restrict__ W3, const float* __restrict__ b3,
    float* __restrict__ out, int n_nodes)
{
    __shared__ float sW1[96];   // [6][16]
    __shared__ float sb1[16];
    __shared__ float sW2[256];  // [16][16]
    __shared__ float sb2[16];
    __shared__ float sW3[48];   // [16][3]
    __shared__ float sb3[3];

    const int t = threadIdx.x;
    if (t < 96)  sW1[t] = W1[t];
    if (t < 16)  sb1[t] = b1[t];
    sW2[t] = W2[t];            // 256 threads, 256 entries
    if (t < 16)  sb2[t] = b2[t];
    if (t < 48)  sW3[t] = W3[t];
    if (t < 3)   sb3[t] = b3[t];
    __syncthreads();

    const int i = blockIdx.x * 256 + t;
    if (i >= n_nodes) return;

    float in6[6];
    in6[0] = x[3 * i + 0];
    in6[1] = x[3 * i + 1];
    in6[2] = x[3 * i + 2];
    in6[3] = out[3 * i + 0];   // agg accumulated by edge_scatter_kernel
    in6[4] = out[3 * i + 1];
    in6[5] = out[3 * i + 2];

    float h1[16];
#pragma unroll
    for (int j = 0; j < 16; ++j) {
        float s = sb1[j];
#pragma unroll
        for (int k = 0; k < 6; ++k) s = fmaf(in6[k], sW1[k * 16 + j], s);
        h1[j] = fmaxf(s, 0.0f);
    }

    float h2[16];
#pragma unroll
    for (int j = 0; j < 16; ++j) {
        float s = sb2[j];
#pragma unroll
        for (int k = 0; k < 16; ++k) s = fmaf(h1[k], sW2[k * 16 + j], s);
        h2[j] = fmaxf(s, 0.0f);
    }

    float o[3];
#pragma unroll
    for (int c = 0; c < 3; ++c) {
        float s = sb3[c];
#pragma unroll
        for (int j = 0; j < 16; ++j) s = fmaf(h2[j], sW3[j * 3 + c], s);
        o[c] = s;
    }

    out[3 * i + 0] = o[0];
    out[3 * i + 1] = o[1];
    out[3 * i + 2] = o[2];
}

extern "C" void kernel_launch(void* const* d_in, const int* in_sizes, int n_in,
                              void* d_out, int out_size, void* d_ws, size_t ws_size,
                              hipStream_t stream) {
    const float* x   = (const float*)d_in[0];
    const int*   ei  = (const int*)d_in[1];   // [2, E] int32 (harness converts int64 -> int32)
    // d_in[2] edge_attr, d_in[3] u, d_in[4] batch: unused by the reference node model
    const float* W1  = (const float*)d_in[5];
    const float* b1  = (const float*)d_in[6];
    const float* W2  = (const float*)d_in[7];
    const float* b2  = (const float*)d_in[8];
    const float* W3  = (const float*)d_in[9];
    const float* b3  = (const float*)d_in[10];

    const int n_nodes = in_sizes[0] / 3;
    const int n_edges = in_sizes[1] / 2;
    const int* rows = ei;            // edge_index[0]
    const int* cols = ei + n_edges;  // edge_index[1]

    float* out = (float*)d_out;

    // 1) zero the agg accumulator (d_out)
    hipMemsetAsync(d_out, 0, (size_t)out_size * sizeof(float), stream);

    // 2) scatter-add x[row] into out[col]
    const int eblocks = 8192;  // grid-stride over ~6.5M int4 groups
    edge_scatter_kernel<<<eblocks, 256, 0, stream>>>(rows, cols, x, out, n_edges);

    // 3) per-node MLP, in-place on d_out
    const int nblocks = (n_nodes + 255) / 256;
    node_mlp_kernel<<<nblocks, 256, 0, stream>>>(x, W1, b1, W2, b2, W3, b3, out, n_nodes);
}

// Round 2
// 980.353 us; speedup vs baseline: 3.9022x; 3.9022x over previous
//
#include <hip/hip_runtime.h>

// NodeModel: agg = segment_sum(x[row], col); h = concat(x, agg); out = MLP(h).
//
// Fast path: on-device counting-sort of edges by col-bucket (col>>SHIFT),
// then per-bucket LDS accumulation -> no global float atomics at all.
// Fallback path (ws too small): direct global atomicAdd scatter.

#define SHIFT 10
#define BSIZE 1024            // nodes per bucket = 1<<SHIFT
#define MAXNB 1024            // max buckets supported (N <= MAXNB<<SHIFT = 1M... 977 used)
#define NBLK  512             // edge chunks (blocks) for hist/scatter

// ---------------- fast path kernels ----------------

__global__ __launch_bounds__(256) void hist_kernel(
    const int* __restrict__ cols, int* __restrict__ hist,
    int nb, int chunk, int n_edges)
{
    __shared__ int lh[MAXNB];
    const int t = threadIdx.x, b = blockIdx.x;
    for (int k = t; k < nb; k += 256) lh[k] = 0;
    __syncthreads();

    long long s = (long long)b * chunk;
    long long e = s + chunk; if (e > n_edges) e = n_edges;
    if (s < e) {
        const int n = (int)(e - s);
        const int n4 = n >> 2;
        const int4* __restrict__ c4p = reinterpret_cast<const int4*>(cols + s);
        for (int i = t; i < n4; i += 256) {
            int4 c = c4p[i];
            atomicAdd(&lh[(unsigned)c.x >> SHIFT], 1);
            atomicAdd(&lh[(unsigned)c.y >> SHIFT], 1);
            atomicAdd(&lh[(unsigned)c.z >> SHIFT], 1);
            atomicAdd(&lh[(unsigned)c.w >> SHIFT], 1);
        }
        for (int i = (n4 << 2) + t; i < n; i += 256)
            atomicAdd(&lh[(unsigned)cols[s + i] >> SHIFT], 1);
    }
    __syncthreads();
    for (int k = t; k < nb; k += 256) hist[(size_t)b * nb + k] = lh[k];
}

// For each bucket k: exclusive-scan hist[b][k] along b; colTotal[k] = total.
__global__ __launch_bounds__(NBLK) void scan_blocks_kernel(
    int* __restrict__ hist, int* __restrict__ colTotal, int nb)
{
    __shared__ int sd[NBLK];
    const int t = threadIdx.x, k = blockIdx.x;
    const int v = hist[(size_t)t * nb + k];
    sd[t] = v; __syncthreads();
#pragma unroll
    for (int off = 1; off < NBLK; off <<= 1) {
        int a = (t >= off) ? sd[t - off] : 0;
        __syncthreads();
        sd[t] += a;
        __syncthreads();
    }
    hist[(size_t)t * nb + k] = sd[t] - v;   // exclusive along b
    if (t == NBLK - 1) colTotal[k] = sd[t];
}

// Exclusive scan of colTotal -> bucketStart[0..nb], bucketStart[nb] = E.
__global__ __launch_bounds__(MAXNB) void scan_buckets_kernel(
    const int* __restrict__ colTotal, int* __restrict__ bucketStart, int nb)
{
    __shared__ int sd[MAXNB];
    const int t = threadIdx.x;
    const int v = (t < nb) ? colTotal[t] : 0;
    sd[t] = v; __syncthreads();
#pragma unroll
    for (int off = 1; off < MAXNB; off <<= 1) {
        int a = (t >= off) ? sd[t - off] : 0;
        __syncthreads();
        sd[t] += a;
        __syncthreads();
    }
    if (t < nb) bucketStart[t] = sd[t] - v;
    if (t == 0) bucketStart[nb] = sd[MAXNB - 1];
}

__global__ __launch_bounds__(256) void scatter_kernel(
    const int* __restrict__ rows, const int* __restrict__ cols,
    const int* __restrict__ hist, const int* __restrict__ bucketStart,
    unsigned* __restrict__ packed, int nb, int chunk, int n_edges)
{
    __shared__ int lc[MAXNB];
    const int t = threadIdx.x, b = blockIdx.x;
    for (int k = t; k < nb; k += 256)
        lc[k] = bucketStart[k] + hist[(size_t)b * nb + k];
    __syncthreads();

    long long s = (long long)b * chunk;
    long long e = s + chunk; if (e > n_edges) e = n_edges;
    if (s < e) {
        const int n = (int)(e - s);
        const int n4 = n >> 2;
        const int4* __restrict__ c4p = reinterpret_cast<const int4*>(cols + s);
        const int4* __restrict__ r4p = reinterpret_cast<const int4*>(rows + s);
        for (int i = t; i < n4; i += 256) {
            int4 c = c4p[i];
            int4 r = r4p[i];
            int p;
            p = atomicAdd(&lc[(unsigned)c.x >> SHIFT], 1);
            packed[p] = ((unsigned)r.x << SHIFT) | ((unsigned)c.x & (BSIZE - 1));
            p = atomicAdd(&lc[(unsigned)c.y >> SHIFT], 1);
            packed[p] = ((unsigned)r.y << SHIFT) | ((unsigned)c.y & (BSIZE - 1));
            p = atomicAdd(&lc[(unsigned)c.z >> SHIFT], 1);
            packed[p] = ((unsigned)r.z << SHIFT) | ((unsigned)c.z & (BSIZE - 1));
            p = atomicAdd(&lc[(unsigned)c.w >> SHIFT], 1);
            packed[p] = ((unsigned)r.w << SHIFT) | ((unsigned)c.w & (BSIZE - 1));
        }
        for (int i = (n4 << 2) + t; i < n; i += 256) {
            int c = cols[s + i], r = rows[s + i];
            int p = atomicAdd(&lc[(unsigned)c >> SHIFT], 1);
            packed[p] = ((unsigned)r << SHIFT) | ((unsigned)c & (BSIZE - 1));
        }
    }
}

__global__ __launch_bounds__(256) void bucket_agg_kernel(
    const unsigned* __restrict__ packed, const float* __restrict__ x,
    const int* __restrict__ bucketStart, float* __restrict__ out,
    int n_nodes)
{
    __shared__ float acc[BSIZE * 3];   // 12 KB
    const int t = threadIdx.x, k = blockIdx.x;
    for (int f = t; f < BSIZE * 3; f += 256) acc[f] = 0.0f;
    __syncthreads();

    const int s = bucketStart[k];
    const int e = bucketStart[k + 1];
    for (int i = s + t; i < e; i += 256) {
        const unsigned p = packed[i];
        const int r = (int)(p >> SHIFT);
        const int j = (int)(p & (BSIZE - 1));
        const float* __restrict__ xs = x + 3ll * r;
        atomicAdd(&acc[j * 3 + 0], xs[0]);
        atomicAdd(&acc[j * 3 + 1], xs[1]);
        atomicAdd(&acc[j * 3 + 2], xs[2]);
    }
    __syncthreads();

    const long long base = (long long)k << SHIFT;
    long long lim = (long long)n_nodes - base;
    if (lim > BSIZE) lim = BSIZE;
    if (lim <= 0) return;
    float* __restrict__ o = out + base * 3;
    const int fl = (int)lim * 3;
    for (int f = t; f < fl; f += 256) o[f] = acc[f];
}

// ---------------- fallback (global atomics) ----------------

__global__ __launch_bounds__(256) void edge_scatter_kernel(
    const int* __restrict__ rows, const int* __restrict__ cols,
    const float* __restrict__ x, float* __restrict__ agg, int n_edges)
{
    const long long tid = (long long)blockIdx.x * blockDim.x + threadIdx.x;
    const long long stride = (long long)gridDim.x * blockDim.x;
    for (long long i = tid; i < n_edges; i += stride) {
        int r = rows[i], c = cols[i];
        const float* xs = x + 3ll * r; float* a = agg + 3ll * c;
        atomicAdd(a + 0, xs[0]); atomicAdd(a + 1, xs[1]); atomicAdd(a + 2, xs[2]);
    }
}

// ---------------- node MLP (reads agg from d_out in place) ----------------

__global__ __launch_bounds__(256) void node_mlp_kernel(
    const float* __restrict__ x,
    const float* __restrict__ W1, const float* __restrict__ b1,
    const float* __restrict__ W2, const float* __restrict__ b2,
    const float* __restrict__ W3, const float* __restrict__ b3,
    float* __restrict__ out, int n_nodes)
{
    __shared__ float sW1[96];
    __shared__ float sb1[16];
    __shared__ float sW2[256];
    __shared__ float sb2[16];
    __shared__ float sW3[48];
    __shared__ float sb3[3];

    const int t = threadIdx.x;
    if (t < 96)  sW1[t] = W1[t];
    if (t < 16)  sb1[t] = b1[t];
    sW2[t] = W2[t];
    if (t < 16)  sb2[t] = b2[t];
    if (t < 48)  sW3[t] = W3[t];
    if (t < 3)   sb3[t] = b3[t];
    __syncthreads();

    const int i = blockIdx.x * 256 + t;
    if (i >= n_nodes) return;

    float in6[6];
    in6[0] = x[3 * i + 0];
    in6[1] = x[3 * i + 1];
    in6[2] = x[3 * i + 2];
    in6[3] = out[3 * i + 0];
    in6[4] = out[3 * i + 1];
    in6[5] = out[3 * i + 2];

    float h1[16];
#pragma unroll
    for (int j = 0; j < 16; ++j) {
        float s = sb1[j];
#pragma unroll
        for (int k = 0; k < 6; ++k) s = fmaf(in6[k], sW1[k * 16 + j], s);
        h1[j] = fmaxf(s, 0.0f);
    }

    float h2[16];
#pragma unroll
    for (int j = 0; j < 16; ++j) {
        float s = sb2[j];
#pragma unroll
        for (int k = 0; k < 16; ++k) s = fmaf(h1[k], sW2[k * 16 + j], s);
        h2[j] = fmaxf(s, 0.0f);
    }

    float o[3];
#pragma unroll
    for (int c = 0; c < 3; ++c) {
        float s = sb3[c];
#pragma unroll
        for (int j = 0; j < 16; ++j) s = fmaf(h2[j], sW3[j * 3 + c], s);
        o[c] = s;
    }

    out[3 * i + 0] = o[0];
    out[3 * i + 1] = o[1];
    out[3 * i + 2] = o[2];
}

extern "C" void kernel_launch(void* const* d_in, const int* in_sizes, int n_in,
                              void* d_out, int out_size, void* d_ws, size_t ws_size,
                              hipStream_t stream) {
    const float* x   = (const float*)d_in[0];
    const int*   ei  = (const int*)d_in[1];   // [2, E] int32
    const float* W1  = (const float*)d_in[5];
    const float* b1  = (const float*)d_in[6];
    const float* W2  = (const float*)d_in[7];
    const float* b2  = (const float*)d_in[8];
    const float* W3  = (const float*)d_in[9];
    const float* b3  = (const float*)d_in[10];

    const int n_nodes = in_sizes[0] / 3;
    const int n_edges = in_sizes[1] / 2;
    const int* rows = ei;            // edge_index[0]
    const int* cols = ei + n_edges;  // edge_index[1]
    float* out = (float*)d_out;

    const int nb = (n_nodes + BSIZE - 1) >> SHIFT;

    // ws layout: packed[E] u32 | hist[NBLK*nb] i32 | colTotal[nb] | bucketStart[nb+1]
    const size_t need = (size_t)n_edges * 4 + (size_t)NBLK * nb * 4
                      + (size_t)nb * 4 + (size_t)(nb + 1) * 4;
    const bool fast = (ws_size >= need) && (nb <= MAXNB)
                   && (n_nodes <= (1 << (32 - SHIFT - 1)));  // row fits in packed u32

    if (fast) {
        unsigned* packed    = (unsigned*)d_ws;
        int* hist           = (int*)(packed + n_edges);
        int* colTotal       = hist + (size_t)NBLK * nb;
        int* bucketStart    = colTotal + nb;

        // chunk multiple of 4 so per-block int4 loads stay 16B-aligned
        int chunk = (n_edges + NBLK - 1) / NBLK;
        chunk = (chunk + 3) & ~3;

        hist_kernel<<<NBLK, 256, 0, stream>>>(cols, hist, nb, chunk, n_edges);
        scan_blocks_kernel<<<nb, NBLK, 0, stream>>>(hist, colTotal, nb);
        scan_buckets_kernel<<<1, MAXNB, 0, stream>>>(colTotal, bucketStart, nb);
        scatter_kernel<<<NBLK, 256, 0, stream>>>(rows, cols, hist, bucketStart,
                                                 packed, nb, chunk, n_edges);
        bucket_agg_kernel<<<nb, 256, 0, stream>>>(packed, x, bucketStart, out, n_nodes);
    } else {
        hipMemsetAsync(d_out, 0, (size_t)out_size * sizeof(float), stream);
        edge_scatter_kernel<<<8192, 256, 0, stream>>>(rows, cols, x, out, n_edges);
    }

    const int nblocks = (n_nodes + 255) / 256;
    node_mlp_kernel<<<nblocks, 256, 0, stream>>>(x, W1, b1, W2, b2, W3, b3, out, n_nodes);
}

// Round 3
// 728.151 us; speedup vs baseline: 5.2538x; 1.3464x over previous
//
#include <hip/hip_runtime.h>

// NodeModel: agg = segment_sum(x[row], col); h = concat(x, agg); out = MLP(h).
//
// Fast path: on-device counting-sort of edges by col-bucket (col>>SHIFT),
// then per-bucket LDS accumulation -> no global float atomics at all.
// SHIFT=12: (row<<12)|(col&4095) fits u32 exactly for N < 2^20, and the
// scatter keeps only 245 write cursors/block so L2 write-combining works.
// Fallback path (ws too small / too many nodes): direct global atomicAdd.

#define SHIFT 12
#define BSIZE 4096            // nodes per bucket = 1<<SHIFT
#define MAXNB 1024            // scan_buckets block size (nb must be <= this)
#define NBLK  512             // edge chunks (blocks) for hist/scatter
#define AGG_THREADS 1024      // bucket_agg block size

// ---------------- fast path kernels ----------------

__global__ __launch_bounds__(256) void hist_kernel(
    const int* __restrict__ cols, int* __restrict__ hist,
    int nb, int chunk, int n_edges)
{
    __shared__ int lh[MAXNB];
    const int t = threadIdx.x, b = blockIdx.x;
    for (int k = t; k < nb; k += 256) lh[k] = 0;
    __syncthreads();

    long long s = (long long)b * chunk;
    long long e = s + chunk; if (e > n_edges) e = n_edges;
    if (s < e) {
        const int n = (int)(e - s);
        const int n4 = n >> 2;
        const int4* __restrict__ c4p = reinterpret_cast<const int4*>(cols + s);
        for (int i = t; i < n4; i += 256) {
            int4 c = c4p[i];
            atomicAdd(&lh[(unsigned)c.x >> SHIFT], 1);
            atomicAdd(&lh[(unsigned)c.y >> SHIFT], 1);
            atomicAdd(&lh[(unsigned)c.z >> SHIFT], 1);
            atomicAdd(&lh[(unsigned)c.w >> SHIFT], 1);
        }
        for (int i = (n4 << 2) + t; i < n; i += 256)
            atomicAdd(&lh[(unsigned)cols[s + i] >> SHIFT], 1);
    }
    __syncthreads();
    for (int k = t; k < nb; k += 256) hist[(size_t)b * nb + k] = lh[k];
}

// For each bucket k: exclusive-scan hist[b][k] along b; colTotal[k] = total.
__global__ __launch_bounds__(NBLK) void scan_blocks_kernel(
    int* __restrict__ hist, int* __restrict__ colTotal, int nb)
{
    __shared__ int sd[NBLK];
    const int t = threadIdx.x, k = blockIdx.x;
    const int v = hist[(size_t)t * nb + k];
    sd[t] = v; __syncthreads();
#pragma unroll
    for (int off = 1; off < NBLK; off <<= 1) {
        int a = (t >= off) ? sd[t - off] : 0;
        __syncthreads();
        sd[t] += a;
        __syncthreads();
    }
    hist[(size_t)t * nb + k] = sd[t] - v;   // exclusive along b
    if (t == NBLK - 1) colTotal[k] = sd[t];
}

// Exclusive scan of colTotal -> bucketStart[0..nb], bucketStart[nb] = E.
__global__ __launch_bounds__(MAXNB) void scan_buckets_kernel(
    const int* __restrict__ colTotal, int* __restrict__ bucketStart, int nb)
{
    __shared__ int sd[MAXNB];
    const int t = threadIdx.x;
    const int v = (t < nb) ? colTotal[t] : 0;
    sd[t] = v; __syncthreads();
#pragma unroll
    for (int off = 1; off < MAXNB; off <<= 1) {
        int a = (t >= off) ? sd[t - off] : 0;
        __syncthreads();
        sd[t] += a;
        __syncthreads();
    }
    if (t < nb) bucketStart[t] = sd[t] - v;
    if (t == 0) bucketStart[nb] = sd[MAXNB - 1];
}

__global__ __launch_bounds__(256) void scatter_kernel(
    const int* __restrict__ rows, const int* __restrict__ cols,
    const int* __restrict__ hist, const int* __restrict__ bucketStart,
    unsigned* __restrict__ packed, int nb, int chunk, int n_edges)
{
    __shared__ int lc[MAXNB];
    const int t = threadIdx.x, b = blockIdx.x;
    for (int k = t; k < nb; k += 256)
        lc[k] = bucketStart[k] + hist[(size_t)b * nb + k];
    __syncthreads();

    long long s = (long long)b * chunk;
    long long e = s + chunk; if (e > n_edges) e = n_edges;
    if (s < e) {
        const int n = (int)(e - s);
        const int n4 = n >> 2;
        const int4* __restrict__ c4p = reinterpret_cast<const int4*>(cols + s);
        const int4* __restrict__ r4p = reinterpret_cast<const int4*>(rows + s);
        for (int i = t; i < n4; i += 256) {
            int4 c = c4p[i];
            int4 r = r4p[i];
            int p;
            p = atomicAdd(&lc[(unsigned)c.x >> SHIFT], 1);
            packed[p] = ((unsigned)r.x << SHIFT) | ((unsigned)c.x & (BSIZE - 1));
            p = atomicAdd(&lc[(unsigned)c.y >> SHIFT], 1);
            packed[p] = ((unsigned)r.y << SHIFT) | ((unsigned)c.y & (BSIZE - 1));
            p = atomicAdd(&lc[(unsigned)c.z >> SHIFT], 1);
            packed[p] = ((unsigned)r.z << SHIFT) | ((unsigned)c.z & (BSIZE - 1));
            p = atomicAdd(&lc[(unsigned)c.w >> SHIFT], 1);
            packed[p] = ((unsigned)r.w << SHIFT) | ((unsigned)c.w & (BSIZE - 1));
        }
        for (int i = (n4 << 2) + t; i < n; i += 256) {
            int c = cols[s + i], r = rows[s + i];
            int p = atomicAdd(&lc[(unsigned)c >> SHIFT], 1);
            packed[p] = ((unsigned)r << SHIFT) | ((unsigned)c & (BSIZE - 1));
        }
    }
}

__global__ __launch_bounds__(AGG_THREADS) void bucket_agg_kernel(
    const unsigned* __restrict__ packed, const float* __restrict__ x,
    const int* __restrict__ bucketStart, float* __restrict__ out,
    int n_nodes)
{
    __shared__ float acc[BSIZE * 3];   // 48 KB
    const int t = threadIdx.x, k = blockIdx.x;
    for (int f = t; f < BSIZE * 3; f += AGG_THREADS) acc[f] = 0.0f;
    __syncthreads();

    const int s = bucketStart[k];
    const int e = bucketStart[k + 1];

    int i = s + t;
    // 4-deep unroll: keep 4 packed loads + 12 gather loads in flight
    for (; i + 3 * AGG_THREADS < e; i += 4 * AGG_THREADS) {
        unsigned p0 = packed[i];
        unsigned p1 = packed[i + AGG_THREADS];
        unsigned p2 = packed[i + 2 * AGG_THREADS];
        unsigned p3 = packed[i + 3 * AGG_THREADS];
        const float* xs0 = x + 3ll * (p0 >> SHIFT);
        const float* xs1 = x + 3ll * (p1 >> SHIFT);
        const float* xs2 = x + 3ll * (p2 >> SHIFT);
        const float* xs3 = x + 3ll * (p3 >> SHIFT);
        float a0 = xs0[0], b0 = xs0[1], c0 = xs0[2];
        float a1 = xs1[0], b1 = xs1[1], c1 = xs1[2];
        float a2 = xs2[0], b2 = xs2[1], c2 = xs2[2];
        float a3 = xs3[0], b3 = xs3[1], c3 = xs3[2];
        int j0 = (int)(p0 & (BSIZE - 1)) * 3;
        int j1 = (int)(p1 & (BSIZE - 1)) * 3;
        int j2 = (int)(p2 & (BSIZE - 1)) * 3;
        int j3 = (int)(p3 & (BSIZE - 1)) * 3;
        atomicAdd(&acc[j0 + 0], a0); atomicAdd(&acc[j0 + 1], b0); atomicAdd(&acc[j0 + 2], c0);
        atomicAdd(&acc[j1 + 0], a1); atomicAdd(&acc[j1 + 1], b1); atomicAdd(&acc[j1 + 2], c1);
        atomicAdd(&acc[j2 + 0], a2); atomicAdd(&acc[j2 + 1], b2); atomicAdd(&acc[j2 + 2], c2);
        atomicAdd(&acc[j3 + 0], a3); atomicAdd(&acc[j3 + 1], b3); atomicAdd(&acc[j3 + 2], c3);
    }
    for (; i < e; i += AGG_THREADS) {
        const unsigned p = packed[i];
        const float* __restrict__ xs = x + 3ll * (p >> SHIFT);
        const int j = (int)(p & (BSIZE - 1)) * 3;
        atomicAdd(&acc[j + 0], xs[0]);
        atomicAdd(&acc[j + 1], xs[1]);
        atomicAdd(&acc[j + 2], xs[2]);
    }
    __syncthreads();

    const long long base = (long long)k << SHIFT;
    long long lim = (long long)n_nodes - base;
    if (lim > BSIZE) lim = BSIZE;
    if (lim <= 0) return;
    float* __restrict__ o = out + base * 3;
    const int fl = (int)lim * 3;
    for (int f = t; f < fl; f += AGG_THREADS) o[f] = acc[f];
}

// ---------------- fallback (global atomics) ----------------

__global__ __launch_bounds__(256) void edge_scatter_kernel(
    const int* __restrict__ rows, const int* __restrict__ cols,
    const float* __restrict__ x, float* __restrict__ agg, int n_edges)
{
    const long long tid = (long long)blockIdx.x * blockDim.x + threadIdx.x;
    const long long stride = (long long)gridDim.x * blockDim.x;
    for (long long i = tid; i < n_edges; i += stride) {
        int r = rows[i], c = cols[i];
        const float* xs = x + 3ll * r; float* a = agg + 3ll * c;
        atomicAdd(a + 0, xs[0]); atomicAdd(a + 1, xs[1]); atomicAdd(a + 2, xs[2]);
    }
}

// ---------------- node MLP (reads agg from d_out in place) ----------------

__global__ __launch_bounds__(256) void node_mlp_kernel(
    const float* __restrict__ x,
    const float* __restrict__ W1, const float* __restrict__ b1,
    const float* __restrict__ W2, const float* __restrict__ b2,
    const float* __restrict__ W3, const float* __restrict__ b3,
    float* __restrict__ out, int n_nodes)
{
    __shared__ float sW1[96];
    __shared__ float sb1[16];
    __shared__ float sW2[256];
    __shared__ float sb2[16];
    __shared__ float sW3[48];
    __shared__ float sb3[3];

    const int t = threadIdx.x;
    if (t < 96)  sW1[t] = W1[t];
    if (t < 16)  sb1[t] = b1[t];
    sW2[t] = W2[t];
    if (t < 16)  sb2[t] = b2[t];
    if (t < 48)  sW3[t] = W3[t];
    if (t < 3)   sb3[t] = b3[t];
    __syncthreads();

    const int i = blockIdx.x * 256 + t;
    if (i >= n_nodes) return;

    float in6[6];
    in6[0] = x[3 * i + 0];
    in6[1] = x[3 * i + 1];
    in6[2] = x[3 * i + 2];
    in6[3] = out[3 * i + 0];
    in6[4] = out[3 * i + 1];
    in6[5] = out[3 * i + 2];

    float h1[16];
#pragma unroll
    for (int j = 0; j < 16; ++j) {
        float s = sb1[j];
#pragma unroll
        for (int k = 0; k < 6; ++k) s = fmaf(in6[k], sW1[k * 16 + j], s);
        h1[j] = fmaxf(s, 0.0f);
    }

    float h2[16];
#pragma unroll
    for (int j = 0; j < 16; ++j) {
        float s = sb2[j];
#pragma unroll
        for (int k = 0; k < 16; ++k) s = fmaf(h1[k], sW2[k * 16 + j], s);
        h2[j] = fmaxf(s, 0.0f);
    }

    float o[3];
#pragma unroll
    for (int c = 0; c < 3; ++c) {
        float s = sb3[c];
#pragma unroll
        for (int j = 0; j < 16; ++j) s = fmaf(h2[j], sW3[j * 3 + c], s);
        o[c] = s;
    }

    out[3 * i + 0] = o[0];
    out[3 * i + 1] = o[1];
    out[3 * i + 2] = o[2];
}

extern "C" void kernel_launch(void* const* d_in, const int* in_sizes, int n_in,
                              void* d_out, int out_size, void* d_ws, size_t ws_size,
                              hipStream_t stream) {
    const float* x   = (const float*)d_in[0];
    const int*   ei  = (const int*)d_in[1];   // [2, E] int32
    const float* W1  = (const float*)d_in[5];
    const float* b1  = (const float*)d_in[6];
    const float* W2  = (const float*)d_in[7];
    const float* b2  = (const float*)d_in[8];
    const float* W3  = (const float*)d_in[9];
    const float* b3  = (const float*)d_in[10];

    const int n_nodes = in_sizes[0] / 3;
    const int n_edges = in_sizes[1] / 2;
    const int* rows = ei;            // edge_index[0]
    const int* cols = ei + n_edges;  // edge_index[1]
    float* out = (float*)d_out;

    const int nb = (n_nodes + BSIZE - 1) >> SHIFT;

    // ws layout: packed[E] u32 | hist[NBLK*nb] i32 | colTotal[nb] | bucketStart[nb+1]
    const size_t need = (size_t)n_edges * 4 + (size_t)NBLK * nb * 4
                      + (size_t)nb * 4 + (size_t)(nb + 1) * 4;
    const bool fast = (ws_size >= need) && (nb <= MAXNB)
                   && (n_nodes <= (1 << (32 - SHIFT)));  // (row<<SHIFT)|local fits u32

    if (fast) {
        unsigned* packed    = (unsigned*)d_ws;
        int* hist           = (int*)(packed + n_edges);
        int* colTotal       = hist + (size_t)NBLK * nb;
        int* bucketStart    = colTotal + nb;

        // chunk multiple of 4 so per-block int4 loads stay 16B-aligned
        int chunk = (n_edges + NBLK - 1) / NBLK;
        chunk = (chunk + 3) & ~3;

        hist_kernel<<<NBLK, 256, 0, stream>>>(cols, hist, nb, chunk, n_edges);
        scan_blocks_kernel<<<nb, NBLK, 0, stream>>>(hist, colTotal, nb);
        scan_buckets_kernel<<<1, MAXNB, 0, stream>>>(colTotal, bucketStart, nb);
        scatter_kernel<<<NBLK, 256, 0, stream>>>(rows, cols, hist, bucketStart,
                                                 packed, nb, chunk, n_edges);
        bucket_agg_kernel<<<nb, AGG_THREADS, 0, stream>>>(packed, x, bucketStart, out, n_nodes);
    } else {
        hipMemsetAsync(d_out, 0, (size_t)out_size * sizeof(float), stream);
        edge_scatter_kernel<<<8192, 256, 0, stream>>>(rows, cols, x, out, n_edges);
    }

    const int nblocks = (n_nodes + 255) / 256;
    node_mlp_kernel<<<nblocks, 256, 0, stream>>>(x, W1, b1, W2, b2, W3, b3, out, n_nodes);
}